// Round 1
// baseline (2338.356 us; speedup 1.0000x reference)
//
#include <hip/hip_runtime.h>
#include <cmath>

#define DEV static __device__ __forceinline__

DEV float leaky_f(float x) { return x > 0.f ? x : 0.2f * x; }

// ---------------- FiLM: gamma/beta from global features ----------------
__global__ void k_film(const float* __restrict__ gf,
                       const float* __restrict__ gW, const float* __restrict__ gb,
                       const float* __restrict__ bW, const float* __restrict__ bb,
                       float* __restrict__ out) {
  int j = threadIdx.x;
  if (j >= 64) return;
  float g = gb[j], b = bb[j];
  for (int k = 0; k < 128; ++k) {
    float v = gf[k];
    g += v * gW[k * 64 + j];
    b += v * bW[k * 64 + j];
  }
  out[j] = 1.0f + g;   // store (1+gamma)
  out[64 + j] = b;
}

// ---------------- input projection + FiLM: x64 = film(relu(nf@ipW+b)) ----------------
__global__ __launch_bounds__(256) void k_input(
    const float* __restrict__ nf, const float* __restrict__ ipW,
    const float* __restrict__ ipb, const float* __restrict__ gbv,
    float* __restrict__ x64, int N) {
  int lane = threadIdx.x & 63;
  int n = blockIdx.x * 4 + (threadIdx.x >> 6);
  if (n >= N) return;
  const float* row = nf + (size_t)n * 5;
  float acc = ipb[lane];
#pragma unroll
  for (int k = 0; k < 5; ++k) acc += row[k] * ipW[k * 64 + lane];
  acc = fmaxf(acc, 0.f);
  acc = acc * gbv[lane] + gbv[64 + lane];
  x64[(size_t)n * 64 + lane] = acc;
}

// ---------------- edge encoder: edge_feat = relu(attr@W1+b1)@W2+b2 ----------------
__global__ __launch_bounds__(256) void k_edgefeat(
    const float* __restrict__ pos, const int* __restrict__ src, const int* __restrict__ dst,
    const float* __restrict__ W1, const float* __restrict__ b1,
    const float* __restrict__ W2, const float* __restrict__ b2,
    float* __restrict__ ef, int E) {
  __shared__ float sW1[160], sb1[32], sW2[1024], sb2[32];
  for (int i = threadIdx.x; i < 160; i += 256) sW1[i] = W1[i];
  for (int i = threadIdx.x; i < 1024; i += 256) sW2[i] = W2[i];
  if (threadIdx.x < 32) { sb1[threadIdx.x] = b1[threadIdx.x]; sb2[threadIdx.x] = b2[threadIdx.x]; }
  __syncthreads();
  int e = blockIdx.x * 256 + threadIdx.x;
  if (e >= E) return;
  int s = src[e], d = dst[e];
  float dx = pos[d * 3 + 0] - pos[s * 3 + 0];
  float dy = pos[d * 3 + 1] - pos[s * 3 + 1];
  float dz = pos[d * 3 + 2] - pos[s * 3 + 2];
  float dist = sqrtf(dx * dx + dy * dy + dz * dz);
  dist = fmaxf(dist, 1e-6f);
  float inv = 1.f / dist;
  float attr[5] = {dx * inv, dy * inv, dz * inv, dist, logf(dist)};
  float h[32];
#pragma unroll
  for (int j = 0; j < 32; ++j) {
    float a = sb1[j];
#pragma unroll
    for (int k = 0; k < 5; ++k) a += attr[k] * sW1[k * 32 + j];
    h[j] = fmaxf(a, 0.f);
  }
  float* o = ef + (size_t)e * 32;
#pragma unroll 4
  for (int j = 0; j < 32; ++j) {
    float a = sb2[j];
#pragma unroll
    for (int k = 0; k < 32; ++k) a += h[k] * sW2[k * 32 + j];
    o[j] = a;
  }
}

// ---------------- CSR build ----------------
__global__ void k_count(const int* __restrict__ dst, int* __restrict__ cnt, int E) {
  int e = blockIdx.x * 256 + threadIdx.x;
  if (e < E) atomicAdd(&cnt[dst[e]], 1);
}

__global__ void k_scan(const int* __restrict__ cnt, int* __restrict__ off, int N) {
  __shared__ int s[256];
  int tid = threadIdx.x;
  int carry = 0;
  for (int base = 0; base < N; base += 256) {
    int i = base + tid;
    int v = (i < N) ? cnt[i] : 0;
    __syncthreads();
    s[tid] = v;
    __syncthreads();
    int x = v;
    for (int d = 1; d < 256; d <<= 1) {
      int t = (tid >= d) ? s[tid - d] : 0;
      __syncthreads();
      x += t;
      s[tid] = x;
      __syncthreads();
    }
    if (i < N) off[i] = carry + x - v;  // exclusive scan
    carry += s[255];
  }
  if (tid == 0) off[N] = carry;
}

__global__ void k_scatter(const int* __restrict__ dst, const int* __restrict__ off,
                          int* __restrict__ cur, int* __restrict__ eid, int E) {
  int e = blockIdx.x * 256 + threadIdx.x;
  if (e < E) {
    int d = dst[e];
    int p = atomicAdd(&cur[d], 1);
    eid[off[d] + p] = e;
  }
}

// ---------------- tiled fp32 GEMM: C[M x 256] = A[M x K] @ B[K x 256] + bias ----------------
__global__ __launch_bounds__(256) void k_gemm(
    const float* __restrict__ A, const float* __restrict__ B,
    const float* __restrict__ bias, float* __restrict__ C, int M, int K) {
  __shared__ float As[16][64];
  __shared__ float Bs[16][68];
  int tid = threadIdx.x;
  int tx = tid & 15, ty = tid >> 4;
  int brow = blockIdx.x * 64, bcol = blockIdx.y * 64;
  float acc[4][4] = {};
  for (int k0 = 0; k0 < K; k0 += 16) {
    {
      int idx = tid * 4;
      int r = idx >> 4, kk = idx & 15;
      int row = brow + r; if (row > M - 1) row = M - 1;
      const float4 a4 = *(const float4*)(A + (size_t)row * K + k0 + kk);
      As[kk + 0][r] = a4.x; As[kk + 1][r] = a4.y; As[kk + 2][r] = a4.z; As[kk + 3][r] = a4.w;
    }
    {
      int kk = tid >> 4;
      int c = (tid & 15) * 4;
      const float4 b4 = *(const float4*)(B + (size_t)(k0 + kk) * 256 + bcol + c);
      *(float4*)(&Bs[kk][c]) = b4;
    }
    __syncthreads();
#pragma unroll
    for (int k = 0; k < 16; ++k) {
      float a[4], b[4];
#pragma unroll
      for (int i = 0; i < 4; ++i) a[i] = As[k][ty * 4 + i];
#pragma unroll
      for (int j = 0; j < 4; ++j) b[j] = Bs[k][tx * 4 + j];
#pragma unroll
      for (int i = 0; i < 4; ++i)
#pragma unroll
        for (int j = 0; j < 4; ++j) acc[i][j] += a[i] * b[j];
    }
    __syncthreads();
  }
#pragma unroll
  for (int i = 0; i < 4; ++i) {
    int row = brow + ty * 4 + i;
    if (row < M) {
      float4 r;
      r.x = acc[i][0] + bias[bcol + tx * 4 + 0];
      r.y = acc[i][1] + bias[bcol + tx * 4 + 1];
      r.z = acc[i][2] + bias[bcol + tx * 4 + 2];
      r.w = acc[i][3] + bias[bcol + tx * 4 + 3];
      *(float4*)(C + (size_t)row * 256 + bcol + tx * 4) = r;
    }
  }
}

// ---------------- edge logits: thread per edge, We staged in LDS ----------------
__global__ __launch_bounds__(256) void k_elogits(
    const float* __restrict__ ef, const int* __restrict__ src, const int* __restrict__ dst,
    const float* __restrict__ xl, const float* __restrict__ xr,
    const float* __restrict__ We_l, const float* __restrict__ att_l,
    float* __restrict__ logits, int E) {
  __shared__ float sWe[32 * 256];
  __shared__ float sAtt[256];
  for (int i = threadIdx.x; i < 32 * 256; i += 256) sWe[i] = We_l[i];
  if (threadIdx.x < 256) sAtt[threadIdx.x] = att_l[threadIdx.x];
  __syncthreads();
  int e = blockIdx.x * 256 + threadIdx.x;
  if (e >= E) return;
  float f[32];
  const float4* efp = (const float4*)(ef + (size_t)e * 32);
#pragma unroll
  for (int q = 0; q < 8; ++q) {
    float4 v = efp[q];
    f[q * 4 + 0] = v.x; f[q * 4 + 1] = v.y; f[q * 4 + 2] = v.z; f[q * 4 + 3] = v.w;
  }
  int s = src[e], d = dst[e];
  const float4* xs = (const float4*)(xl + (size_t)s * 256);
  const float4* xd = (const float4*)(xr + (size_t)d * 256);
  float lgs[4];
#pragma unroll
  for (int h = 0; h < 4; ++h) {
    float acc = 0.f;
#pragma unroll 2
    for (int c4 = h * 16; c4 < h * 16 + 16; ++c4) {
      float4 efv = {0.f, 0.f, 0.f, 0.f};
#pragma unroll
      for (int j = 0; j < 32; ++j) {
        float fj = f[j];
        const float4 w = *(const float4*)(&sWe[j * 256 + c4 * 4]);
        efv.x += fj * w.x; efv.y += fj * w.y; efv.z += fj * w.z; efv.w += fj * w.w;
      }
      float4 a = xs[c4], b = xd[c4];
      float g0 = leaky_f(a.x + b.x + efv.x);
      float g1 = leaky_f(a.y + b.y + efv.y);
      float g2 = leaky_f(a.z + b.z + efv.z);
      float g3 = leaky_f(a.w + b.w + efv.w);
      const float4 at = *(const float4*)(&sAtt[c4 * 4]);
      acc += g0 * at.x + g1 * at.y + g2 * at.z + g3 * at.w;
    }
    lgs[h] = acc;
  }
  float4 outv = {lgs[0], lgs[1], lgs[2], lgs[3]};
  *(float4*)(logits + (size_t)e * 4) = outv;
}

// ---------------- segment softmax + aggregate + conv_b + LN + relu + residual ----------------
__global__ __launch_bounds__(256) void k_agg(
    const int* __restrict__ off, const int* __restrict__ eid, const int* __restrict__ src,
    const float* __restrict__ logits, const float* __restrict__ xl,
    const float* __restrict__ xprev, const float* __restrict__ convb,
    const float* __restrict__ lng, const float* __restrict__ lnb,
    float* __restrict__ xout, int N) {
  int lane = threadIdx.x & 63;
  int n = blockIdx.x * 4 + (threadIdx.x >> 6);
  if (n >= N) return;
  int o0 = off[n], o1 = off[n + 1];
  int deg = o1 - o0;
  float m0 = -3.4e38f, m1 = m0, m2 = m0, m3 = m0;
  for (int t = lane; t < deg; t += 64) {
    int e = eid[o0 + t];
    const float4 lg = *(const float4*)(logits + (size_t)e * 4);
    m0 = fmaxf(m0, lg.x); m1 = fmaxf(m1, lg.y); m2 = fmaxf(m2, lg.z); m3 = fmaxf(m3, lg.w);
  }
#pragma unroll
  for (int d = 1; d < 64; d <<= 1) {
    m0 = fmaxf(m0, __shfl_xor(m0, d));
    m1 = fmaxf(m1, __shfl_xor(m1, d));
    m2 = fmaxf(m2, __shfl_xor(m2, d));
    m3 = fmaxf(m3, __shfl_xor(m3, d));
  }
  float s0 = 0.f, s1 = 0.f, s2 = 0.f, s3 = 0.f;
  for (int t = lane; t < deg; t += 64) {
    int e = eid[o0 + t];
    const float4 lg = *(const float4*)(logits + (size_t)e * 4);
    s0 += expf(lg.x - m0); s1 += expf(lg.y - m1);
    s2 += expf(lg.z - m2); s3 += expf(lg.w - m3);
  }
#pragma unroll
  for (int d = 1; d < 64; d <<= 1) {
    s0 += __shfl_xor(s0, d); s1 += __shfl_xor(s1, d);
    s2 += __shfl_xor(s2, d); s3 += __shfl_xor(s3, d);
  }
  float i0 = deg > 0 ? 1.f / s0 : 0.f;
  float i1 = deg > 0 ? 1.f / s1 : 0.f;
  float i2 = deg > 0 ? 1.f / s2 : 0.f;
  float i3 = deg > 0 ? 1.f / s3 : 0.f;
  float a0 = 0.f, a1 = 0.f, a2 = 0.f, a3 = 0.f;
  for (int t = 0; t < deg; ++t) {
    int e = eid[o0 + t];
    int sN = src[e];
    const float4 lg = *(const float4*)(logits + (size_t)e * 4);
    float w0 = expf(lg.x - m0) * i0;
    float w1 = expf(lg.y - m1) * i1;
    float w2 = expf(lg.z - m2) * i2;
    float w3 = expf(lg.w - m3) * i3;
    const float* xsrow = xl + (size_t)sN * 256;
    a0 += w0 * xsrow[lane];
    a1 += w1 * xsrow[64 + lane];
    a2 += w2 * xsrow[128 + lane];
    a3 += w3 * xsrow[192 + lane];
  }
  float v0 = a0 + convb[lane];
  float v1 = a1 + convb[64 + lane];
  float v2 = a2 + convb[128 + lane];
  float v3 = a3 + convb[192 + lane];
  float ssum = v0 + v1 + v2 + v3;
  float ssq = v0 * v0 + v1 * v1 + v2 * v2 + v3 * v3;
#pragma unroll
  for (int d = 1; d < 64; d <<= 1) {
    ssum += __shfl_xor(ssum, d);
    ssq += __shfl_xor(ssq, d);
  }
  float mu = ssum * (1.0f / 256.0f);
  float var = ssq * (1.0f / 256.0f) - mu * mu;
  float rstd = rsqrtf(var + 1e-5f);
  const float* xp = xprev + (size_t)n * 256;
  float* xo = xout + (size_t)n * 256;
  xo[lane]       = fmaxf((v0 - mu) * rstd * lng[lane]       + lnb[lane],       0.f) + xp[lane];
  xo[64 + lane]  = fmaxf((v1 - mu) * rstd * lng[64 + lane]  + lnb[64 + lane],  0.f) + xp[64 + lane];
  xo[128 + lane] = fmaxf((v2 - mu) * rstd * lng[128 + lane] + lnb[128 + lane], 0.f) + xp[128 + lane];
  xo[192 + lane] = fmaxf((v3 - mu) * rstd * lng[192 + lane] + lnb[192 + lane], 0.f) + xp[192 + lane];
}

// ---------------- output projection: relu(x@W1+b1)@W2+b2 ----------------
__global__ __launch_bounds__(256) void k_out(
    const float* __restrict__ x, const float* __restrict__ W1, const float* __restrict__ b1,
    const float* __restrict__ W2, const float* __restrict__ b2,
    float* __restrict__ out, int N) {
  __shared__ float sW1[256 * 64];  // 64 KB
  for (int i = threadIdx.x; i < 256 * 64; i += 256) sW1[i] = W1[i];
  __syncthreads();
  int lane = threadIdx.x & 63;
  int wv = threadIdx.x >> 6;
  for (int n = blockIdx.x * 4 + wv; n < N; n += gridDim.x * 4) {
    const float* xrow = x + (size_t)n * 256;
    float h = b1[lane];
    for (int k = 0; k < 256; ++k) h += xrow[k] * sW1[k * 64 + lane];
    h = fmaxf(h, 0.f);
    float y[5];
#pragma unroll
    for (int o = 0; o < 5; ++o) {
      float p = h * W2[lane * 5 + o];
#pragma unroll
      for (int d = 1; d < 64; d <<= 1) p += __shfl_xor(p, d);
      y[o] = p;
    }
    if (lane == 0) {
#pragma unroll
      for (int o = 0; o < 5; ++o) out[(size_t)n * 5 + o] = y[o] + b2[o];
    }
  }
}

extern "C" void kernel_launch(void* const* d_in, const int* in_sizes, int n_in,
                              void* d_out, int out_size, void* d_ws, size_t ws_size,
                              hipStream_t stream) {
  const float* nf      = (const float*)d_in[0];
  const float* gf      = (const float*)d_in[1];
  const int*   eidx    = (const int*)d_in[2];
  const float* pos     = (const float*)d_in[3];
  const float* ip_W    = (const float*)d_in[4];
  const float* ip_b    = (const float*)d_in[5];
  const float* film_gW = (const float*)d_in[6];
  const float* film_gb = (const float*)d_in[7];
  const float* film_bW = (const float*)d_in[8];
  const float* film_bb = (const float*)d_in[9];
  const float* ee_W1   = (const float*)d_in[10];
  const float* ee_b1   = (const float*)d_in[11];
  const float* ee_W2   = (const float*)d_in[12];
  const float* ee_b2   = (const float*)d_in[13];
  const float* res_W   = (const float*)d_in[14];
  const float* res_b   = (const float*)d_in[15];
  const float* l0_Wl   = (const float*)d_in[16];
  const float* l0_bl   = (const float*)d_in[17];
  const float* l0_Wr   = (const float*)d_in[18];
  const float* l0_br   = (const float*)d_in[19];
  const float* Wl      = (const float*)d_in[20];
  const float* bl      = (const float*)d_in[21];
  const float* Wr      = (const float*)d_in[22];
  const float* br      = (const float*)d_in[23];
  const float* We      = (const float*)d_in[24];
  const float* att     = (const float*)d_in[25];
  const float* conv_b  = (const float*)d_in[26];
  const float* ln_g    = (const float*)d_in[27];
  const float* ln_b    = (const float*)d_in[28];
  const float* op_W1   = (const float*)d_in[29];
  const float* op_b1   = (const float*)d_in[30];
  const float* op_W2   = (const float*)d_in[31];
  const float* op_b2   = (const float*)d_in[32];

  const int N = in_sizes[0] / 5;
  const int E = in_sizes[2] / 2;
  const int* src = eidx;
  const int* dst = eidx + E;

  float* ws = (float*)d_ws;
  size_t o = 0;
  auto alloc = [&](size_t nflt) {
    float* p = ws + o;
    o += (nflt + 63) & ~(size_t)63;
    return p;
  };
  float* gb      = alloc(128);
  float* x64     = alloc((size_t)N * 64);
  float* ef32    = alloc((size_t)E * 32);
  float* logits  = alloc((size_t)E * 4);
  int*   cnt     = (int*)alloc(2 * (size_t)N);
  int*   cur     = cnt + N;
  int*   csroff  = (int*)alloc((size_t)N + 1);
  int*   csreid  = (int*)alloc((size_t)E);
  float* xl      = alloc((size_t)N * 256);
  float* xr      = alloc((size_t)N * 256);
  float* xA      = alloc((size_t)N * 256);
  float* xB      = alloc((size_t)N * 256);
  float* xp0     = alloc((size_t)N * 256);

  (void)ws_size; (void)n_in; (void)out_size;

  hipMemsetAsync(cnt, 0, 2 * (size_t)N * sizeof(int), stream);

  k_film<<<1, 64, 0, stream>>>(gf, film_gW, film_gb, film_bW, film_bb, gb);
  k_input<<<(N + 3) / 4, 256, 0, stream>>>(nf, ip_W, ip_b, gb, x64, N);
  k_edgefeat<<<(E + 255) / 256, 256, 0, stream>>>(pos, src, dst, ee_W1, ee_b1, ee_W2, ee_b2, ef32, E);
  k_count<<<(E + 255) / 256, 256, 0, stream>>>(dst, cnt, E);
  k_scan<<<1, 256, 0, stream>>>(cnt, csroff, N);
  k_scatter<<<(E + 255) / 256, 256, 0, stream>>>(dst, csroff, cur, csreid, E);

  const float* xin = x64;
  for (int layer = 0; layer < 6; ++layer) {
    const int K = (layer == 0) ? 64 : 256;
    const float* Wl_p = (layer == 0) ? l0_Wl : (Wl + (size_t)(layer - 1) * 256 * 256);
    const float* bl_p = (layer == 0) ? l0_bl : (bl + (size_t)(layer - 1) * 256);
    const float* Wr_p = (layer == 0) ? l0_Wr : (Wr + (size_t)(layer - 1) * 256 * 256);
    const float* br_p = (layer == 0) ? l0_br : (br + (size_t)(layer - 1) * 256);

    dim3 gg((N + 63) / 64, 4);
    k_gemm<<<gg, 256, 0, stream>>>(xin, Wl_p, bl_p, xl, N, K);
    k_gemm<<<gg, 256, 0, stream>>>(xin, Wr_p, br_p, xr, N, K);

    const float* prev;
    if (layer == 0) {
      k_gemm<<<gg, 256, 0, stream>>>(xin, res_W, res_b, xp0, N, 64);
      prev = xp0;
    } else {
      prev = xin;
    }

    k_elogits<<<(E + 255) / 256, 256, 0, stream>>>(
        ef32, src, dst, xl, xr, We + (size_t)layer * 32 * 256, att + (size_t)layer * 256,
        logits, E);

    float* xout = (layer & 1) ? xB : xA;
    k_agg<<<(N + 3) / 4, 256, 0, stream>>>(
        csroff, csreid, src, logits, xl, prev,
        conv_b + (size_t)layer * 256, ln_g + (size_t)layer * 256, ln_b + (size_t)layer * 256,
        xout, N);
    xin = xout;
  }

  k_out<<<512, 256, 0, stream>>>(xin, op_W1, op_b1, op_W2, op_b2, (float*)d_out, N);
}